// Round 13
// baseline (28.076 us; speedup 1.0000x reference)
//
#include <hip/hip_runtime.h>
#include <hip/hip_bf16.h>

// KAN layer: out[n,i] = sum_{g,d} splines[i,g,d] * relu(1 - |x[n,d] - grid[g]|)
// B=8192, D=192, G=192, O=16.
//
// x,grid in [0,1] => relu is identity. Piecewise-linear in x per d:
//   sum_g s*(1-|x-r_g|) = Cp(g*) - x*A(g*),  g* = floor(x*191)
// A = 2P - T, Cp = T - U + 2Q; P,Q inclusive prefix sums of s and s*grid
// over g. tab[d][g][i] = u32 {lo=bf16(A), hi=bf16(Cp)} (2.36 MB in d_ws).
//
// R12 lesson: NT loads (L1 bypass) REGRESS -> gather L1 reuse is real and
// is the remaining lever. R13: d-outer/n-wide main: block = 256 n x 24-d
// chunk; at each d the 256 gathers hit one 12 KB table row (192 lines) ->
// L1-resident; L2 line-requests 1.57M -> ~0.9M. x tile staged in LDS.
// Grid 256 = 1 block/CU, chunk = bid&7 keeps per-XCD L2 slice pinning.

#define Dn 192
#define Gn 192
#define On 16
#define Bn 8192

#define DSPLIT 8
#define DCHUNK (Dn / DSPLIT)    // 24
#define NPBm 256                // n's per main block
#define TPBm 512                // threads per main block

__device__ __forceinline__ unsigned short f2bf(float f) {
    union { float f; unsigned u; } v; v.f = f;
    unsigned r = v.u + 0x7FFF + ((v.u >> 16) & 1);   // RTN-even
    return (unsigned short)(r >> 16);
}

// ---------------- precompute (R11-exact): one wave per (d-pair, i) -------
__global__ __launch_bounds__(256) void kan_pre(const float* __restrict__ sp,
                                               const float* __restrict__ grid,
                                               unsigned* __restrict__ tab,
                                               float* __restrict__ out) {
    int gtid = blockIdx.x * blockDim.x + threadIdx.x;
    if (gtid < Bn * On / 4)                     // zero out[] for main's atomics
        ((float4*)out)[gtid] = make_float4(0.f, 0.f, 0.f, 0.f);

    int w = gtid >> 6;              // wave id, 0..1535 (no tail)
    int lane = threadIdx.x & 63;
    int dp = w >> 4;                // d-pair 0..95
    int i  = w & 15;
    int d  = dp * 2;

    int g0 = lane * 3;              // 192 = 64 lanes * 3 g's each
    const float* s_base = sp + (size_t)i * Gn * Dn + d;   // splines[i,g,d]
    float2 s0 = *(const float2*)&s_base[(size_t)(g0 + 0) * Dn];
    float2 s1 = *(const float2*)&s_base[(size_t)(g0 + 1) * Dn];
    float2 s2 = *(const float2*)&s_base[(size_t)(g0 + 2) * Dn];
    float r0 = grid[g0 + 0], r1 = grid[g0 + 1], r2 = grid[g0 + 2];

    #pragma unroll
    for (int j = 0; j < 2; ++j) {   // the two d's of the pair
        float v0 = (j == 0) ? s0.x : s0.y;
        float v1 = (j == 0) ? s1.x : s1.y;
        float v2 = (j == 0) ? s2.x : s2.y;
        float q0 = v0 * r0, q1 = v1 * r1, q2 = v2 * r2;

        float lp1 = v0 + v1, lp2 = lp1 + v2;
        float lq1 = q0 + q1, lq2 = lq1 + q2;
        float sP = lp2, sQ = lq2;
        #pragma unroll
        for (int off = 1; off < 64; off <<= 1) {
            float pP = __shfl_up(sP, off);
            float pQ = __shfl_up(sQ, off);
            if (lane >= off) { sP += pP; sQ += pQ; }
        }
        float exP = sP - lp2, exQ = sQ - lq2;
        float T = __shfl(sP, 63);
        float U = __shfl(sQ, 63);

        float P[3] = { exP + v0, exP + lp1, exP + lp2 };
        float Q[3] = { exQ + q0, exQ + lq1, exQ + lq2 };

        #pragma unroll
        for (int k = 0; k < 3; ++k) {
            int g = g0 + k;
            float A  = 2.0f * P[k] - T;
            float Cp = T - U + 2.0f * Q[k];
            tab[((size_t)(d + j) * Gn + g) * On + i] =
                (unsigned)f2bf(A) | ((unsigned)f2bf(Cp) << 16);
        }
    }
}

// ---------------- main: block = (256 n, d-chunk); d-outer, L1-hot rows ---
__global__ __launch_bounds__(TPBm) void kan_main(const float* __restrict__ x,
                                                 const unsigned* __restrict__ tab,
                                                 float* __restrict__ out) {
    __shared__ float xs[NPBm * DCHUNK];     // 24 KB: x tile [256 n][24 d]
    int t = threadIdx.x;
    unsigned bid = blockIdx.x;              // 256 blocks = 32/XCD = 1/CU
    int chunk = bid & 7;                    // d-chunk == XCD under round-robin
    int n0 = (int)(bid >> 3) * NPBm;
    int d0 = chunk * DCHUNK;

    // stage x[n0..n0+255][d0..d0+23] -> xs (row-chunk copy, float4)
    {
        const float4* xsrc = (const float4*)x;   // rows: 48 float4
        float4* xd = (float4*)xs;
        #pragma unroll
        for (int j = 0; j < (NPBm * DCHUNK / 4) / TPBm; ++j) {  // 3
            int idx = t + j * TPBm;
            int r = idx / 6, c = idx % 6;        // 6 float4 per row-chunk
            xd[idx] = xsrc[(size_t)(n0 + r) * 48 + chunk * 6 + c];
        }
    }
    __syncthreads();

    int i    = t & 15;
    int nsub = t >> 4;                      // 0..31
    const unsigned* tb = tab + (size_t)d0 * Gn * On + i;

    float acc[8] = {0.f, 0.f, 0.f, 0.f, 0.f, 0.f, 0.f, 0.f};
    for (int dd = 0; dd < DCHUNK; ++dd) {   // d-outer: 12 KB table row L1-hot
        const unsigned* tbd = tb + (size_t)dd * Gn * On;
        float v[8];
        unsigned e[8];
        #pragma unroll
        for (int k = 0; k < 8; ++k) {       // 8 independent gathers in flight
            float vv = xs[(nsub + 32 * k) * DCHUNK + dd];   // LDS broadcast
            int g = (int)(vv * 191.0f);
            g = (g < 0) ? 0 : (g > 191 ? 191 : g);
            v[k] = vv;
            e[k] = tbd[(size_t)g * On];
        }
        #pragma unroll
        for (int k = 0; k < 8; ++k) {
            union { unsigned u; float f; } A, C;
            A.u = e[k] << 16;               // bf16 lo -> f32
            C.u = e[k] & 0xFFFF0000u;       // bf16 hi -> f32
            acc[k] += C.f;
            acc[k] = fmaf(-v[k], A.f, acc[k]);   // acc += Cp - x*A
        }
    }
    #pragma unroll
    for (int k = 0; k < 8; ++k)
        atomicAdd(&out[(size_t)(n0 + nsub + 32 * k) * On + i], acc[k]);
}

// ---------------- fallback (ws too small): direct computation ------------
__global__ __launch_bounds__(256) void kan_naive(const float* __restrict__ x,
                                                 const float* __restrict__ sp,
                                                 const float* __restrict__ grid,
                                                 float* __restrict__ out) {
    __shared__ float xs[Dn];
    __shared__ float gsh[Gn];
    __shared__ float red[4];
    int n = blockIdx.x;
    int t = threadIdx.x;
    if (t < Dn) { xs[t] = x[(size_t)n * Dn + t]; gsh[t] = grid[t]; }
    __syncthreads();
    float acc[On];
    #pragma unroll
    for (int i = 0; i < On; ++i) acc[i] = 0.0f;
    for (int idx = t; idx < Gn * Dn; idx += 256) {
        int g = idx / Dn;
        int d = idx - g * Dn;
        float b = fmaxf(0.0f, 1.0f - fabsf(xs[d] - gsh[g]));
        #pragma unroll
        for (int i = 0; i < On; ++i)
            acc[i] += sp[(size_t)i * Gn * Dn + idx] * b;
    }
    for (int i = 0; i < On; ++i) {
        float v = acc[i];
        #pragma unroll
        for (int off = 32; off > 0; off >>= 1) v += __shfl_down(v, off);
        if ((t & 63) == 0) red[t >> 6] = v;
        __syncthreads();
        if (t == 0) out[(size_t)n * On + i] = red[0] + red[1] + red[2] + red[3];
        __syncthreads();
    }
}

extern "C" void kernel_launch(void* const* d_in, const int* in_sizes, int n_in,
                              void* d_out, int out_size, void* d_ws, size_t ws_size,
                              hipStream_t stream) {
    const float* x    = (const float*)d_in[0];
    const float* sp   = (const float*)d_in[1];
    const float* grid = (const float*)d_in[2];
    float* out = (float*)d_out;

    const size_t TAB_BYTES = (size_t)Dn * Gn * On * sizeof(unsigned);  // 2.36 MB
    if (ws_size >= TAB_BYTES) {
        unsigned* tab = (unsigned*)d_ws;
        kan_pre<<<384, 256, 0, stream>>>(sp, grid, tab, out);          // 1536 waves
        kan_main<<<(Bn / NPBm) * DSPLIT, TPBm, 0, stream>>>(x, tab, out);  // 256 blocks
    } else {
        kan_naive<<<Bn, 256, 0, stream>>>(x, sp, grid, out);
    }
}

// Round 14
// 22.230 us; speedup vs baseline: 1.2630x; 1.2630x over previous
//
#include <hip/hip_runtime.h>
#include <hip/hip_bf16.h>

// KAN layer: out[n,i] = sum_{g,d} splines[i,g,d] * relu(1 - |x[n,d] - grid[g]|)
// B=8192, D=192, G=192, O=16.
//
// x,grid in [0,1] => relu is identity. Piecewise-linear in x per d:
//   sum_g s*(1-|x-r_g|) = Cp(g*) - x*A(g*),  g* = floor(x*191)
// A = 2P - T, Cp = T - U + 2Q; P,Q inclusive prefix sums of s and s*grid
// over g. tab[d][g][i] = u32 {lo=bf16(A), hi=bf16(Cp)} (2.36 MB in d_ws);
// main = one 64B-line L2 gather per (n,d) 16-lane group (minimal bytes:
// 16 i x {A,Cp} x 2B = 64B per lookup, all consumed).
//
// FINAL (R11 champion, 22.1us). Fixed budget: ~10.7us harness overhead
// (R7-measured), pre ~2us, main ~8.5us = 1.57M random 64B lines at the
// measured ~12TB/s random-line rate. Falsified alternatives: NT loads
// (R12, L1 reuse is real), L1-hot d-outer tiling (R13, occupancy loss),
// deeper MLP (R9, null), LDS-gather (R6), cooperative fusion (R7,
// grid.sync ~150us), flag handshake (R10, stale L2 polling ~130us),
// staged-LDS pre (R3/R8, loses to scattered+TLP).

#define Dn 192
#define Gn 192
#define On 16
#define Bn 8192

#define DSPLIT 8
#define DCHUNK (Dn / DSPLIT)    // 24

__device__ __forceinline__ unsigned short f2bf(float f) {
    union { float f; unsigned u; } v; v.f = f;
    unsigned r = v.u + 0x7FFF + ((v.u >> 16) & 1);   // RTN-even
    return (unsigned short)(r >> 16);
}

// ---------------- precompute: one wave per (d-pair, i) --------------------
// 384 blocks x 256 thr = 1536 waves. Lane handles 3 g's x 2 d's (float2
// loads, 8B-aligned since d is even). Also zeroes out[] for main's atomics.
__global__ __launch_bounds__(256) void kan_pre(const float* __restrict__ sp,
                                               const float* __restrict__ grid,
                                               unsigned* __restrict__ tab,
                                               float* __restrict__ out) {
    int gtid = blockIdx.x * blockDim.x + threadIdx.x;
    if (gtid < Bn * On / 4)                     // 32768 float4 = 131072 floats
        ((float4*)out)[gtid] = make_float4(0.f, 0.f, 0.f, 0.f);

    int w = gtid >> 6;              // wave id, 0..1535 (no tail)
    int lane = threadIdx.x & 63;
    int dp = w >> 4;                // d-pair 0..95
    int i  = w & 15;
    int d  = dp * 2;

    int g0 = lane * 3;              // 192 = 64 lanes * 3 g's each
    const float* s_base = sp + (size_t)i * Gn * Dn + d;   // splines[i,g,d]
    // float2 covers (d, d+1) for each of this lane's 3 g's
    float2 s0 = *(const float2*)&s_base[(size_t)(g0 + 0) * Dn];
    float2 s1 = *(const float2*)&s_base[(size_t)(g0 + 1) * Dn];
    float2 s2 = *(const float2*)&s_base[(size_t)(g0 + 2) * Dn];
    float r0 = grid[g0 + 0], r1 = grid[g0 + 1], r2 = grid[g0 + 2];

    #pragma unroll
    for (int j = 0; j < 2; ++j) {   // the two d's of the pair
        float v0 = (j == 0) ? s0.x : s0.y;
        float v1 = (j == 0) ? s1.x : s1.y;
        float v2 = (j == 0) ? s2.x : s2.y;
        float q0 = v0 * r0, q1 = v1 * r1, q2 = v2 * r2;

        float lp1 = v0 + v1, lp2 = lp1 + v2;   // local inclusive prefix of P
        float lq1 = q0 + q1, lq2 = lq1 + q2;   // local inclusive prefix of Q
        float sP = lp2, sQ = lq2;
        #pragma unroll
        for (int off = 1; off < 64; off <<= 1) {
            float pP = __shfl_up(sP, off);
            float pQ = __shfl_up(sQ, off);
            if (lane >= off) { sP += pP; sQ += pQ; }
        }
        float exP = sP - lp2, exQ = sQ - lq2;  // exclusive carry
        float T = __shfl(sP, 63);
        float U = __shfl(sQ, 63);

        float P[3] = { exP + v0, exP + lp1, exP + lp2 };
        float Q[3] = { exQ + q0, exQ + lq1, exQ + lq2 };

        #pragma unroll
        for (int k = 0; k < 3; ++k) {
            int g = g0 + k;
            float A  = 2.0f * P[k] - T;
            float Cp = T - U + 2.0f * Q[k];
            tab[((size_t)(d + j) * Gn + g) * On + i] =
                (unsigned)f2bf(A) | ((unsigned)f2bf(Cp) << 16);
        }
    }
}

// ---------------- main: thread = (i, n), d-chunk = bid&7 ------------------
__global__ __launch_bounds__(256) void kan_main(const float* __restrict__ x,
                                                const unsigned* __restrict__ tab,
                                                float* __restrict__ out) {
    int t = threadIdx.x;
    int i  = t & 15;
    int nn = t >> 4;                        // 0..15
    unsigned bid = blockIdx.x;              // 4096 blocks
    int chunk = bid & 7;                    // d-chunk == XCD under round-robin
    int n = (bid >> 3) * 16 + nn;
    int d0 = chunk * DCHUNK;

    const float4* xr = (const float4*)(x + (size_t)n * Dn + d0);  // 6 float4
    const unsigned* tb = tab + (size_t)d0 * Gn * On + i;

    float acc = 0.0f;
    #pragma unroll
    for (int d4 = 0; d4 < DCHUNK / 4; ++d4) {   // 6 iterations
        float4 xv = xr[d4];
        float vx[4] = { xv.x, xv.y, xv.z, xv.w };
        #pragma unroll
        for (int k = 0; k < 4; ++k) {
            float v = vx[k];
            int g = (int)(v * 191.0f);
            g = (g < 0) ? 0 : (g > 191 ? 191 : g);
            unsigned e = tb[((d4 * 4 + k) * Gn + g) * On];
            union { unsigned u; float f; } A, C;
            A.u = e << 16;            // bf16 lo -> f32
            C.u = e & 0xFFFF0000u;    // bf16 hi -> f32
            acc += C.f;
            acc = fmaf(-v, A.f, acc); // acc += Cp - x*A
        }
    }
    atomicAdd(&out[(size_t)n * On + i], acc);
}

// ---------------- fallback (ws too small): direct computation ------------
__global__ __launch_bounds__(256) void kan_naive(const float* __restrict__ x,
                                                 const float* __restrict__ sp,
                                                 const float* __restrict__ grid,
                                                 float* __restrict__ out) {
    __shared__ float xs[Dn];
    __shared__ float gsh[Gn];
    __shared__ float red[4];
    int n = blockIdx.x;
    int t = threadIdx.x;
    if (t < Dn) { xs[t] = x[(size_t)n * Dn + t]; gsh[t] = grid[t]; }
    __syncthreads();
    float acc[On];
    #pragma unroll
    for (int i = 0; i < On; ++i) acc[i] = 0.0f;
    for (int idx = t; idx < Gn * Dn; idx += 256) {
        int g = idx / Dn;
        int d = idx - g * Dn;
        float b = fmaxf(0.0f, 1.0f - fabsf(xs[d] - gsh[g]));
        #pragma unroll
        for (int i = 0; i < On; ++i)
            acc[i] += sp[(size_t)i * Gn * Dn + idx] * b;
    }
    for (int i = 0; i < On; ++i) {
        float v = acc[i];
        #pragma unroll
        for (int off = 32; off > 0; off >>= 1) v += __shfl_down(v, off);
        if ((t & 63) == 0) red[t >> 6] = v;
        __syncthreads();
        if (t == 0) out[(size_t)n * On + i] = red[0] + red[1] + red[2] + red[3];
        __syncthreads();
    }
}

extern "C" void kernel_launch(void* const* d_in, const int* in_sizes, int n_in,
                              void* d_out, int out_size, void* d_ws, size_t ws_size,
                              hipStream_t stream) {
    const float* x    = (const float*)d_in[0];
    const float* sp   = (const float*)d_in[1];
    const float* grid = (const float*)d_in[2];
    float* out = (float*)d_out;

    const size_t TAB_BYTES = (size_t)Dn * Gn * On * sizeof(unsigned);  // 2.36 MB
    if (ws_size >= TAB_BYTES) {
        unsigned* tab = (unsigned*)d_ws;
        kan_pre<<<384, 256, 0, stream>>>(sp, grid, tab, out);           // 1536 waves
        kan_main<<<(Bn / 16) * DSPLIT, 256, 0, stream>>>(x, tab, out);  // 4096 blocks
    } else {
        kan_naive<<<Bn, 256, 0, stream>>>(x, sp, grid, out);
    }
}